// Round 5
// baseline (2082.523 us; speedup 1.0000x reference)
//
#include <hip/hip_runtime.h>

// Conv2D 7x7 VALID, fp32, 8192x8192 -> 8186x8186.
// No-LDS direct conv: each thread computes an 8x4 output micro-tile with
// vertical register reuse (rolling accumulators over 14 input rows, each row
// loaded once as 3x float4). Horizontal halo overlap absorbed by L1/L2.
// No barriers, no LDS -> high occupancy, deep load pipelining.
// Weights forced to SGPRs via readfirstlane (1 SGPR operand per v_fma).

#define IH 8192
#define IW 8192
#define OH 8186
#define OW 8186

#define TRPT 8     // output rows per thread
#define TCPT 4     // output cols per thread
#define BTX 32     // threads x
#define BTY 8      // threads y
#define TILW (BTX * TCPT)   // 128 output cols per block
#define TILH (BTY * TRPT)   // 64 output rows per block

__global__ __launch_bounds__(256, 6)
void conv7x7_direct(const float* __restrict__ x,
                    const float* __restrict__ wgt,
                    const float* __restrict__ bias,
                    float* __restrict__ out) {
    const int tid = threadIdx.x;
    const int tx = tid & (BTX - 1);
    const int ty = tid >> 5;

    const int CB = blockIdx.x * TILW;          // block col base
    const int R  = blockIdx.y * TILH;          // block row base

    // ---- weights + bias -> scalar registers ----
    float w[49];
#pragma unroll
    for (int i = 0; i < 49; ++i)
        w[i] = __uint_as_float(__builtin_amdgcn_readfirstlane(
                   __float_as_uint(wgt[i])));
    const float b0 = __uint_as_float(__builtin_amdgcn_readfirstlane(
                         __float_as_uint(bias[0])));

    // ---- per-thread geometry ----
    const int ocol = CB + tx * TCPT;           // first output col
    const int orow0 = R + ty * TRPT;           // first output row

    // load columns (clamped so the 16B loads stay in-bounds; clamped lanes
    // only ever feed masked-out outputs)
    int c0 = ocol;     if (c0 > IW - 4) c0 = IW - 4;
    int c1 = ocol + 4; if (c1 > IW - 4) c1 = IW - 4;
    int c2 = ocol + 8; if (c2 > IW - 4) c2 = IW - 4;

    float acc[TRPT][TCPT];
#pragma unroll
    for (int o = 0; o < TRPT; ++o)
#pragma unroll
        for (int oc = 0; oc < TCPT; ++oc) acc[o][oc] = b0;

#pragma unroll
    for (int ir = 0; ir < TRPT + 6; ++ir) {
        int gr = orow0 + ir;
        if (gr > IH - 1) gr = IH - 1;          // feeds only masked outputs
        const size_t rb = (size_t)gr * IW;
        const float4 fa = *reinterpret_cast<const float4*>(x + rb + c0);
        const float4 fb = *reinterpret_cast<const float4*>(x + rb + c1);
        const float4 fc = *reinterpret_cast<const float4*>(x + rb + c2);
        float f[12];
        f[0] = fa.x; f[1] = fa.y; f[2]  = fa.z; f[3]  = fa.w;
        f[4] = fb.x; f[5] = fb.y; f[6]  = fb.z; f[7]  = fb.w;
        f[8] = fc.x; f[9] = fc.y; f[10] = fc.z; f[11] = fc.w;

#pragma unroll
        for (int o = 0; o < TRPT; ++o) {
            const int wr = ir - o;             // kernel row for output row o
            if (wr < 0 || wr > 6) continue;    // compile-time after unroll
#pragma unroll
            for (int oc = 0; oc < TCPT; ++oc) {
#pragma unroll
                for (int j = 0; j < 7; ++j) {
                    acc[o][oc] += f[oc + j] * w[wr * 7 + j];
                }
            }
        }
    }

    // ---- store 8x4 micro-tile (float2, 8B-aligned; masked at edges) ----
    const bool p0 = (ocol + 1) < OW;
    const bool p1 = (ocol + 3) < OW;
#pragma unroll
    for (int o = 0; o < TRPT; ++o) {
        const int gr = orow0 + o;
        if (gr < OH) {
            float* p = out + (size_t)gr * OW + ocol;
            if (p0) *reinterpret_cast<float2*>(p + 0) =
                make_float2(acc[o][0], acc[o][1]);
            if (p1) *reinterpret_cast<float2*>(p + 2) =
                make_float2(acc[o][2], acc[o][3]);
        }
    }
}

extern "C" void kernel_launch(void* const* d_in, const int* in_sizes, int n_in,
                              void* d_out, int out_size, void* d_ws, size_t ws_size,
                              hipStream_t stream) {
    const float* x    = (const float*)d_in[0];
    const float* wgt  = (const float*)d_in[1];
    const float* bias = (const float*)d_in[2];
    float* out = (float*)d_out;

    dim3 grid((OW + TILW - 1) / TILW,    // 64
              (OH + TILH - 1) / TILH);   // 128
    conv7x7_direct<<<grid, dim3(256), 0, stream>>>(x, wgt, bias, out);
}